// Round 2
// baseline (1899.448 us; speedup 1.0000x reference)
//
#include <hip/hip_runtime.h>
#include <hip/hip_bf16.h>
#include <cstdint>
#include <cstddef>

#define EMB 128
#define NLIG 32768
#define NREC 262144
#define NGRAPH 1024
#define ELIG 327680
#define EREC 2097152
#define BN_EPS 1e-5f

typedef unsigned short ushort_t;
typedef short bf16x8 __attribute__((ext_vector_type(8)));
typedef float f32x4 __attribute__((ext_vector_type(4)));

__device__ __forceinline__ float bf2f(ushort_t u) {
  union { unsigned int i; float f; } v;
  v.i = ((unsigned int)u) << 16;
  return v.f;
}
__device__ __forceinline__ ushort_t f2bf(float f) {
  __hip_bfloat16 h = __float2bfloat16(f);  // RNE
  union { __hip_bfloat16 h; ushort_t u; } v;
  v.h = h;
  return v.u;
}

// ============================ CSR build ============================

__global__ __launch_bounds__(256)
void gk_count(const int* __restrict__ dst, int* __restrict__ cnt, int E) {
  int e = blockIdx.x * 256 + threadIdx.x;
  if (e < E) atomicAdd(&cnt[dst[e]], 1);
}

__global__ __launch_bounds__(256)
void gk_scan1(const int* __restrict__ cnt, int* __restrict__ off,
              int* __restrict__ bsum, int n) {
  __shared__ int sm[256];
  int t = threadIdx.x;
  int base = blockIdx.x * 1024 + t * 4;
  int v0 = (base + 0 < n) ? cnt[base + 0] : 0;
  int v1 = (base + 1 < n) ? cnt[base + 1] : 0;
  int v2 = (base + 2 < n) ? cnt[base + 2] : 0;
  int v3 = (base + 3 < n) ? cnt[base + 3] : 0;
  int loc = v0 + v1 + v2 + v3;
  sm[t] = loc;
  __syncthreads();
  for (int o = 1; o < 256; o <<= 1) {
    int x = (t >= o) ? sm[t - o] : 0;
    __syncthreads();
    sm[t] += x;
    __syncthreads();
  }
  int run = sm[t] - loc;
  if (base + 0 < n) off[base + 0] = run;
  run += v0;
  if (base + 1 < n) off[base + 1] = run;
  run += v1;
  if (base + 2 < n) off[base + 2] = run;
  run += v2;
  if (base + 3 < n) off[base + 3] = run;
  if (t == 255) bsum[blockIdx.x] = sm[255];
}

__global__ __launch_bounds__(256)
void gk_scan2(int* __restrict__ bsum, int nb) {
  __shared__ int sm[256];
  int t = threadIdx.x;
  int v = (t < nb) ? bsum[t] : 0;
  sm[t] = v;
  __syncthreads();
  for (int o = 1; o < 256; o <<= 1) {
    int x = (t >= o) ? sm[t - o] : 0;
    __syncthreads();
    sm[t] += x;
    __syncthreads();
  }
  if (t < nb) bsum[t] = sm[t] - v;
}

__global__ __launch_bounds__(256)
void gk_scan3(int* __restrict__ off, const int* __restrict__ bsum, int n, int E) {
  int i = blockIdx.x * 256 + threadIdx.x;
  if (i < n) off[i] += bsum[i >> 10];
  if (i == 0) off[n] = E;
}

__global__ __launch_bounds__(256)
void gk_copy(int* __restrict__ d, const int* __restrict__ s, int n) {
  int i = blockIdx.x * 256 + threadIdx.x;
  if (i < n) d[i] = s[i];
}

__global__ __launch_bounds__(256)
void gk_fill(const int* __restrict__ src, const int* __restrict__ dst,
             int* __restrict__ cur, int* __restrict__ csr, int E) {
  int e = blockIdx.x * 256 + threadIdx.x;
  if (e < E) {
    int d = dst[e];
    int pos = atomicAdd(&cur[d], 1);
    csr[pos] = src[e];
  }
}

__global__ __launch_bounds__(256)
void gk_dinv(const int* __restrict__ off, float* __restrict__ dinv, int n) {
  int i = blockIdx.x * 256 + threadIdx.x;
  if (i < n) dinv[i] = rsqrtf((float)(off[i + 1] - off[i] + 1));
}

// ============================ encoders ============================

__global__ __launch_bounds__(128)
void gk_ligenc(const int* __restrict__ lig_x, const int* __restrict__ offs,
               const float* __restrict__ emb, ushort_t* __restrict__ A) {
  __shared__ int idx[9];
  int i = blockIdx.x;
  int c = threadIdx.x;
  if (c < 9) idx[c] = lig_x[i * 9 + c] + offs[c];
  __syncthreads();
  float acc = 0.f;
#pragma unroll
  for (int f = 0; f < 9; ++f) acc += emb[(size_t)idx[f] * EMB + c];
  A[(size_t)i * EMB + c] = f2bf(acc);
}

// prep for rec encoder: W[199,128] fp32 -> W^T bf16 [128][256], K zero-padded
__global__ __launch_bounds__(256)
void gk_recw(const float* __restrict__ W, ushort_t* __restrict__ Wt) {
  int idx = blockIdx.x * 256 + threadIdx.x;  // 128*256 = 32768 total
  int c = idx >> 8, k = idx & 255;
  Wt[(size_t)c * 256 + k] = (k < 199) ? f2bf(W[(size_t)k * 128 + c]) : (ushort_t)0;
}

// rec encoder via MFMA: A = bf16(X[262144,199]) @ bf16(W[199,128]) + emb1[xi] + b
// 128x128 tile per block (4 waves). Whole W^T staged to LDS (XOR-swizzled
// 16B chunks, as gk_mm); X streamed per 32-K chunk into a row-padded [128][40]
// bf16 buffer (pad -> 2-way max bank aliasing = free; 16B-aligned ds ops).
// Fragment conventions identical to gk_mm (verified):
// A[m=lane&15][k=quad*8+j]; B[k=quad*8+j][n=lane&15]; C/D col=lane&15,
// row=quad*4+reg.
__global__ __launch_bounds__(256)
void gk_recenc(const float* __restrict__ X, const int* __restrict__ xi,
               const float* __restrict__ emb1, const ushort_t* __restrict__ Wt,
               const float* __restrict__ b, ushort_t* __restrict__ A) {
  __shared__ ushort_t Ws[128 * 256];  // 64 KB
  __shared__ ushort_t Xs[128 * 40];   // 10 KB, one 32-K chunk, row-padded
  const int K = 199;
  int t = threadIdx.x;
  int row0 = blockIdx.x * 128;
  int w = t >> 6, lane = t & 63;
  int m = lane & 15, quad = lane >> 4;
  int rbase = w * 32;

  // stage W^T bf16 (coalesced 16B loads; swizzle chunk ^= (c&15))
  for (int u = t; u < 4096; u += 256) {
    int c = u >> 5, cc = u & 31;
    uint4 v = *(const uint4*)(Wt + (size_t)c * 256 + cc * 8);
    *(uint4*)&Ws[c * 256 + ((cc ^ (c & 15)) * 8)] = v;
  }

  f32x4 acc[2][8];
#pragma unroll
  for (int rt = 0; rt < 2; ++rt)
#pragma unroll
    for (int ct = 0; ct < 8; ++ct) acc[rt][ct] = (f32x4){0.f, 0.f, 0.f, 0.f};

  // 7 chunks of 32 cover K=199 (chunk 7 would be all padding)
  for (int ch = 0; ch < 7; ++ch) {
    int kc = ch * 32;
    __syncthreads();  // protect Xs (and, on ch=0, wait for Ws)
    for (int u = t; u < 512; u += 256) {
      int r = u >> 2, sub = u & 3;
      const float* xr = X + (size_t)(row0 + r) * K + kc + sub * 8;
      ushort_t tmp[8];
#pragma unroll
      for (int j = 0; j < 8; ++j) {
        int k = kc + sub * 8 + j;
        float v = (k < K) ? xr[j] : 0.f;
        tmp[j] = f2bf(v);
      }
      *(uint4*)&Xs[r * 40 + sub * 8] = *(uint4*)tmp;
    }
    __syncthreads();

    bf16x8 a0 = *(const bf16x8*)&Xs[(rbase + m) * 40 + quad * 8];
    bf16x8 a1 = *(const bf16x8*)&Xs[(rbase + 16 + m) * 40 + quad * 8];
    int L = ch * 4 + quad;  // logical 8-wide chunk index into Ws
#pragma unroll
    for (int ct = 0; ct < 8; ++ct) {
      bf16x8 bb = *(const bf16x8*)&Ws[(ct * 16 + m) * 256 + ((L ^ m) * 8)];
      acc[0][ct] = __builtin_amdgcn_mfma_f32_16x16x32_bf16(a0, bb, acc[0][ct], 0, 0, 0);
      acc[1][ct] = __builtin_amdgcn_mfma_f32_16x16x32_bf16(a1, bb, acc[1][ct], 0, 0, 0);
    }
  }

  // epilogue: + b + emb1[xi[row]], bf16 store
  float bcol[8];
#pragma unroll
  for (int ct = 0; ct < 8; ++ct) bcol[ct] = b[ct * 16 + m];
#pragma unroll
  for (int rt = 0; rt < 2; ++rt) {
    int rb = row0 + rbase + rt * 16 + quad * 4;
#pragma unroll
    for (int rr = 0; rr < 4; ++rr) {
      int row = rb + rr;
      const float* e = emb1 + (size_t)xi[row] * 128;
#pragma unroll
      for (int ct = 0; ct < 8; ++ct) {
        int c = ct * 16 + m;
        float v = acc[rt][ct][rr] + bcol[ct] + e[c];
        A[(size_t)row * 128 + c] = f2bf(v);
      }
    }
  }
}

// ======================= per-layer prep =======================
// Computes BN scale/shift from stats, and W^T in bf16.
__global__ __launch_bounds__(256)
void gk_prep(const float* __restrict__ W, const float* __restrict__ stats,
             const float* __restrict__ gamma, const float* __restrict__ beta,
             float inv_n, int donorm, ushort_t* __restrict__ Wt,
             float* __restrict__ bnscl, float* __restrict__ bnsh) {
  int idx = blockIdx.x * 256 + threadIdx.x;
  if (idx < 128) {
    if (donorm) {
      float mu = stats[idx] * inv_n;
      float var = stats[128 + idx] * inv_n - mu * mu;
      float s = gamma[idx] * rsqrtf(var + BN_EPS);
      bnscl[idx] = s;
      bnsh[idx] = beta[idx] - mu * s;
    } else {
      bnscl[idx] = 1.f;
      bnsh[idx] = 0.f;
    }
  }
  int c = idx >> 7, k = idx & 127;
  Wt[(size_t)c * 128 + k] = f2bf(W[(size_t)k * 128 + c]);
}

// ====================== MFMA GCN GEMM ======================
// g_bf = (relu(bn(X_bf)) @ W) * dinv[row], bf16 in/out, MFMA 16x16x32.
// 128x128 tile per block (4 waves). X and W^T staged to LDS bf16 with
// XOR-swizzled 16B chunks (conflict-free, no padding -> exactly 64KB LDS).
// Verified layouts: A[m=lane&15][k=quad*8+j]; B[k=quad*8+j][n=lane&15];
// C/D col=lane&15, row=quad*4+reg.
__global__ __launch_bounds__(256)
void gk_mm(const ushort_t* __restrict__ Xb, const ushort_t* __restrict__ Wt,
           const float* __restrict__ bnscl, const float* __restrict__ bnsh,
           int donorm, const float* __restrict__ dinv,
           ushort_t* __restrict__ gb) {
  __shared__ ushort_t Xs[128 * 128];
  __shared__ ushort_t Ws[128 * 128];
  int t = threadIdx.x;
  int row0 = blockIdx.x * 128;

  // stage X with BN+ReLU (chunk = 8 bf16 = 16B; swizzle chunk ^= (row&15))
  for (int i = t; i < 2048; i += 256) {
    int r = i >> 4, cc = i & 15;
    union { uint4 v; ushort_t s[8]; } u;
    u.v = *(const uint4*)(Xb + (size_t)(row0 + r) * 128 + cc * 8);
    if (donorm) {
#pragma unroll
      for (int j = 0; j < 8; ++j) {
        int k = cc * 8 + j;
        float f = fmaf(bf2f(u.s[j]), bnscl[k], bnsh[k]);
        f = f > 0.f ? f : 0.f;
        u.s[j] = f2bf(f);
      }
    }
    *(uint4*)&Xs[r * 128 + ((cc ^ (r & 15)) * 8)] = u.v;
  }
  // stage W^T (already bf16; swizzle chunk ^= (c&15))
  for (int i = t; i < 2048; i += 256) {
    int c = i >> 4, cc = i & 15;
    uint4 u = *(const uint4*)(Wt + (size_t)c * 128 + cc * 8);
    *(uint4*)&Ws[c * 128 + ((cc ^ (c & 15)) * 8)] = u;
  }
  __syncthreads();

  int w = t >> 6, lane = t & 63;
  int m = lane & 15, quad = lane >> 4;
  int rbase = w * 32;

  f32x4 acc[2][8];
#pragma unroll
  for (int rt = 0; rt < 2; ++rt)
#pragma unroll
    for (int ct = 0; ct < 8; ++ct) acc[rt][ct] = (f32x4){0.f, 0.f, 0.f, 0.f};

#pragma unroll
  for (int kc8 = 0; kc8 < 16; kc8 += 4) {  // K-chunks of 32 (4 chunks of 8)
    int ck = (kc8 + quad) ^ m;             // swizzled chunk index
    bf16x8 a0 = *(const bf16x8*)&Xs[(rbase + m) * 128 + ck * 8];
    bf16x8 a1 = *(const bf16x8*)&Xs[(rbase + 16 + m) * 128 + ck * 8];
#pragma unroll
    for (int ct = 0; ct < 8; ++ct) {
      bf16x8 b = *(const bf16x8*)&Ws[(ct * 16 + m) * 128 + ck * 8];
      acc[0][ct] = __builtin_amdgcn_mfma_f32_16x16x32_bf16(a0, b, acc[0][ct], 0, 0, 0);
      acc[1][ct] = __builtin_amdgcn_mfma_f32_16x16x32_bf16(a1, b, acc[1][ct], 0, 0, 0);
    }
  }

#pragma unroll
  for (int rt = 0; rt < 2; ++rt) {
    int rb = row0 + rbase + rt * 16 + quad * 4;
    float d0 = dinv[rb + 0], d1 = dinv[rb + 1];
    float d2 = dinv[rb + 2], d3 = dinv[rb + 3];
#pragma unroll
    for (int ct = 0; ct < 8; ++ct) {
      int c = ct * 16 + m;
      gb[(size_t)(rb + 0) * 128 + c] = f2bf(acc[rt][ct][0] * d0);
      gb[(size_t)(rb + 1) * 128 + c] = f2bf(acc[rt][ct][1] * d1);
      gb[(size_t)(rb + 2) * 128 + c] = f2bf(acc[rt][ct][2] * d2);
      gb[(size_t)(rb + 3) * 128 + c] = f2bf(acc[rt][ct][3] * d3);
    }
  }
}

// ---------------- aggregation helpers ----------------

struct Quad {
  int i0, i1, i2, i3;
  float m0, m1, m2, m3;
};

__device__ __forceinline__ Quad load_quad(const int* __restrict__ csr,
                                          int e, int e1, int safe) {
  Quad q;
  int c0 = (e + 0 < e1) ? e + 0 : safe;
  int c1 = (e + 1 < e1) ? e + 1 : safe;
  int c2 = (e + 2 < e1) ? e + 2 : safe;
  int c3 = (e + 3 < e1) ? e + 3 : safe;
  q.i0 = csr[c0];
  q.i1 = csr[c1];
  q.i2 = csr[c2];
  q.i3 = csr[c3];
  q.m0 = (e + 0 < e1) ? 1.f : 0.f;
  q.m1 = (e + 1 < e1) ? 1.f : 0.f;
  q.m2 = (e + 2 < e1) ? 1.f : 0.f;
  q.m3 = (e + 3 < e1) ? 1.f : 0.f;
  return q;
}

__device__ __forceinline__ void gather4(const ushort_t* __restrict__ g, int c0,
                                        const Quad& q, unsigned int* v) {
  v[0] = *(const unsigned int*)(g + (size_t)q.i0 * 128 + c0);
  v[1] = *(const unsigned int*)(g + (size_t)q.i1 * 128 + c0);
  v[2] = *(const unsigned int*)(g + (size_t)q.i2 * 128 + c0);
  v[3] = *(const unsigned int*)(g + (size_t)q.i3 * 128 + c0);
}

__device__ __forceinline__ void consume4(float2& acc, const Quad& q,
                                         const unsigned int* v) {
  float lo0 = bf2f((ushort_t)(v[0] & 0xffffu)), hi0 = bf2f((ushort_t)(v[0] >> 16));
  float lo1 = bf2f((ushort_t)(v[1] & 0xffffu)), hi1 = bf2f((ushort_t)(v[1] >> 16));
  float lo2 = bf2f((ushort_t)(v[2] & 0xffffu)), hi2 = bf2f((ushort_t)(v[2] >> 16));
  float lo3 = bf2f((ushort_t)(v[3] & 0xffffu)), hi3 = bf2f((ushort_t)(v[3] >> 16));
  acc.x = fmaf(lo0, q.m0, acc.x); acc.y = fmaf(hi0, q.m0, acc.y);
  acc.x = fmaf(lo1, q.m1, acc.x); acc.y = fmaf(hi1, q.m1, acc.y);
  acc.x = fmaf(lo2, q.m2, acc.x); acc.y = fmaf(hi2, q.m2, acc.y);
  acc.x = fmaf(lo3, q.m3, acc.x); acc.y = fmaf(hi3, q.m3, acc.y);
}

// out[i] = dinv[i]*(g[i] + sum_{e in CSR[i]} g[src_e]) ; bf16 in/out, fp32
// accumulate + BN stats. One 64-lane wave handles TWO rows concurrently.
__global__ __launch_bounds__(256)
void gk_agg(const ushort_t* __restrict__ g, const int* __restrict__ off,
            const int* __restrict__ csr, const float* __restrict__ dinv,
            ushort_t* __restrict__ outb, float* __restrict__ stats) {
  __shared__ float ls[128];
  __shared__ float lss[128];
  int t = threadIdx.x;
  int slot = t >> 6;        // 4 waves per block
  int lane = t & 63;
  int c0 = lane * 2;
  int i0 = blockIdx.x * 32;

  if (t < 128) { ls[t] = 0.f; lss[t] = 0.f; }
  __syncthreads();

  float sx = 0.f, sy = 0.f, ssx = 0.f, ssy = 0.f;

  for (int p = 0; p < 4; ++p) {
    int rA = i0 + slot * 2 + p * 8;
    int rB = rA + 1;
    int eA = off[rA], eA1 = off[rA + 1];
    int eB1 = off[rB + 1];
    int eB = eA1;
    float dA = dinv[rA], dB = dinv[rB];
    unsigned int uA = *(const unsigned int*)(g + (size_t)rA * 128 + c0);
    unsigned int uB = *(const unsigned int*)(g + (size_t)rB * 128 + c0);
    float2 accA = make_float2(bf2f((ushort_t)(uA & 0xffffu)),
                              bf2f((ushort_t)(uA >> 16)));
    float2 accB = make_float2(bf2f((ushort_t)(uB & 0xffffu)),
                              bf2f((ushort_t)(uB >> 16)));
    int safeA = (eA1 > eA) ? eA1 - 1 : 0;
    int safeB = (eB1 > eB) ? eB1 - 1 : 0;

    Quad qA = load_quad(csr, eA, eA1, safeA);
    Quad qB = load_quad(csr, eB, eB1, safeB);
    unsigned int vA[4], vB[4];
    gather4(g, c0, qA, vA);
    gather4(g, c0, qB, vB);
    int e_A = eA + 4, e_B = eB + 4;

    while (e_A < eA1 || e_B < eB1) {
      bool an = e_A < eA1;
      bool bn = e_B < eB1;
      Quad qA2, qB2;
      unsigned int wA[4], wB[4];
      if (an) {
        qA2 = load_quad(csr, e_A, eA1, safeA);
        gather4(g, c0, qA2, wA);
      }
      if (bn) {
        qB2 = load_quad(csr, e_B, eB1, safeB);
        gather4(g, c0, qB2, wB);
      }
      consume4(accA, qA, vA);
      consume4(accB, qB, vB);
      if (an) {
        qA = qA2; vA[0] = wA[0]; vA[1] = wA[1]; vA[2] = wA[2]; vA[3] = wA[3];
        e_A += 4;
      } else {
        qA.m0 = qA.m1 = qA.m2 = qA.m3 = 0.f;
      }
      if (bn) {
        qB = qB2; vB[0] = wB[0]; vB[1] = wB[1]; vB[2] = wB[2]; vB[3] = wB[3];
        e_B += 4;
      } else {
        qB.m0 = qB.m1 = qB.m2 = qB.m3 = 0.f;
      }
    }
    consume4(accA, qA, vA);
    consume4(accB, qB, vB);

    accA.x *= dA; accA.y *= dA;
    accB.x *= dB; accB.y *= dB;
    unsigned int oA = (unsigned int)f2bf(accA.x) | ((unsigned int)f2bf(accA.y) << 16);
    unsigned int oB = (unsigned int)f2bf(accB.x) | ((unsigned int)f2bf(accB.y) << 16);
    *(unsigned int*)(outb + (size_t)rA * 128 + c0) = oA;
    *(unsigned int*)(outb + (size_t)rB * 128 + c0) = oB;
    sx += accA.x + accB.x;
    sy += accA.y + accB.y;
    ssx = fmaf(accA.x, accA.x, ssx); ssx = fmaf(accB.x, accB.x, ssx);
    ssy = fmaf(accA.y, accA.y, ssy); ssy = fmaf(accB.y, accB.y, ssy);
  }

  atomicAdd(&ls[c0 + 0], sx);
  atomicAdd(&ls[c0 + 1], sy);
  atomicAdd(&lss[c0 + 0], ssx);
  atomicAdd(&lss[c0 + 1], ssy);
  __syncthreads();
  if (t < 128) {
    atomicAdd(&stats[t], ls[t]);
    atomicAdd(&stats[t + 128], lss[t]);
  }
}

// per-graph mean of relu(bn(A_bf)) for the last layer
__global__ __launch_bounds__(128)
void gk_pool(const ushort_t* __restrict__ A, const float* __restrict__ stats,
             const float* __restrict__ gamma, const float* __restrict__ beta,
             float inv_n, float* __restrict__ z, int npg, int zoff) {
  int gidx = blockIdx.x;
  int c = threadIdx.x;
  float mu = stats[c] * inv_n;
  float var = stats[128 + c] * inv_n - mu * mu;
  float scl = gamma[c] * rsqrtf(var + BN_EPS);
  float be = beta[c];
  float sum = 0.f;
  int r0 = gidx * npg;
  for (int r = 0; r < npg; ++r) {
    float v = (bf2f(A[(size_t)(r0 + r) * 128 + c]) - mu) * scl + be;
    sum += v > 0.f ? v : 0.f;
  }
  z[(size_t)gidx * 256 + zoff + c] = sum * (1.0f / (float)npg);
}

__global__ __launch_bounds__(128)
void gk_mlp(const float* __restrict__ z, const float* __restrict__ w1,
            const float* __restrict__ b1, const float* __restrict__ w2,
            const float* __restrict__ b2, float* __restrict__ out) {
  __shared__ float zs[256];
  __shared__ float red[128];
  int gidx = blockIdx.x, t = threadIdx.x;
  zs[t] = z[(size_t)gidx * 256 + t];
  zs[t + 128] = z[(size_t)gidx * 256 + 128 + t];
  __syncthreads();
  float acc = b1[t];
  for (int k = 0; k < 256; ++k) acc += zs[k] * w1[(size_t)k * 128 + t];
  acc = (acc > 0.f ? acc : 0.f) * w2[t];
  red[t] = acc;
  __syncthreads();
  for (int o = 64; o > 0; o >>= 1) {
    if (t < o) red[t] += red[t + o];
    __syncthreads();
  }
  if (t == 0) out[gidx] = red[0] + b2[0];
}

// ============================ launch ============================

extern "C" void kernel_launch(void* const* d_in, const int* in_sizes, int n_in,
                              void* d_out, int out_size, void* d_ws, size_t ws_size,
                              hipStream_t stream) {
  (void)in_sizes; (void)n_in; (void)out_size; (void)ws_size;
  const int*   lig_x       = (const int*)  d_in[0];
  const int*   rec_x_int   = (const int*)  d_in[1];
  const float* rec_x_float = (const float*)d_in[2];
  const int*   lig_ei      = (const int*)  d_in[3];
  const int*   rec_ei      = (const int*)  d_in[4];
  const int*   atom_off    = (const int*)  d_in[7];
  const float* atom_emb    = (const float*)d_in[8];
  const float* rec_emb1    = (const float*)d_in[9];
  const float* rec_w       = (const float*)d_in[10];
  const float* rec_b       = (const float*)d_in[11];
  const float* lig_W       = (const float*)d_in[12];
  const float* lig_gamma   = (const float*)d_in[14];
  const float* lig_beta    = (const float*)d_in[15];
  const float* rec_W       = (const float*)d_in[16];
  const float* rec_gamma   = (const float*)d_in[18];
  const float* rec_beta    = (const float*)d_in[19];
  const float* out_w1      = (const float*)d_in[20];
  const float* out_b1      = (const float*)d_in[21];
  const float* out_w2      = (const float*)d_in[22];
  const float* out_b2      = (const float*)d_in[23];
  float* out = (float*)d_out;

  char* p = (char*)d_ws;
  auto alloc = [&](size_t bytes) -> void* {
    void* r = p;
    p += (bytes + 255) & ~(size_t)255;
    return r;
  };
  ushort_t* Ab     = (ushort_t*)alloc((size_t)NREC * EMB * 2);  // features bf16
  ushort_t* Gb     = (ushort_t*)alloc((size_t)NREC * EMB * 2);  // g bf16
  ushort_t* Wtb    = (ushort_t*)alloc((size_t)EMB * EMB * 2);   // W^T bf16
  ushort_t* Wt256  = (ushort_t*)alloc((size_t)EMB * 256 * 2);   // rec_w^T bf16, K-padded
  float* bnscl     = (float*)alloc(128 * 4);
  float* bnsh      = (float*)alloc(128 * 4);
  float* dinv_lig  = (float*)alloc((size_t)NLIG * 4);
  float* dinv_rec  = (float*)alloc((size_t)NREC * 4);
  int*   cnt_lig   = (int*)  alloc((size_t)NLIG * 4);
  int*   cnt_rec   = (int*)  alloc((size_t)NREC * 4);
  int*   off_lig   = (int*)  alloc((size_t)(NLIG + 1) * 4);
  int*   off_rec   = (int*)  alloc((size_t)(NREC + 1) * 4);
  int*   csr_lig   = (int*)  alloc((size_t)ELIG * 4);
  int*   csr_rec   = (int*)  alloc((size_t)EREC * 4);
  int*   bsum_lig  = (int*)  alloc(256 * 4);
  int*   bsum_rec  = (int*)  alloc(256 * 4);
  float* stats     = (float*)alloc(256 * 4);
  float* z         = (float*)alloc((size_t)NGRAPH * 256 * 4);

  // ---- CSR build ----
  hipMemsetAsync(cnt_lig, 0, (size_t)NLIG * 4, stream);
  hipMemsetAsync(cnt_rec, 0, (size_t)NREC * 4, stream);
  gk_count<<<ELIG / 256, 256, 0, stream>>>(lig_ei + ELIG, cnt_lig, ELIG);
  gk_count<<<EREC / 256, 256, 0, stream>>>(rec_ei + EREC, cnt_rec, EREC);
  gk_scan1<<<NLIG / 1024, 256, 0, stream>>>(cnt_lig, off_lig, bsum_lig, NLIG);
  gk_scan2<<<1, 256, 0, stream>>>(bsum_lig, NLIG / 1024);
  gk_scan3<<<NLIG / 256, 256, 0, stream>>>(off_lig, bsum_lig, NLIG, ELIG);
  gk_scan1<<<NREC / 1024, 256, 0, stream>>>(cnt_rec, off_rec, bsum_rec, NREC);
  gk_scan2<<<1, 256, 0, stream>>>(bsum_rec, NREC / 1024);
  gk_scan3<<<NREC / 256, 256, 0, stream>>>(off_rec, bsum_rec, NREC, EREC);
  gk_copy<<<NLIG / 256, 256, 0, stream>>>(cnt_lig, off_lig, NLIG);
  gk_copy<<<NREC / 256, 256, 0, stream>>>(cnt_rec, off_rec, NREC);
  gk_fill<<<ELIG / 256, 256, 0, stream>>>(lig_ei, lig_ei + ELIG, cnt_lig, csr_lig, ELIG);
  gk_fill<<<EREC / 256, 256, 0, stream>>>(rec_ei, rec_ei + EREC, cnt_rec, csr_rec, EREC);
  gk_dinv<<<NLIG / 256, 256, 0, stream>>>(off_lig, dinv_lig, NLIG);
  gk_dinv<<<NREC / 256, 256, 0, stream>>>(off_rec, dinv_rec, NREC);

  auto run_entity = [&](const float* Wall, const float* gamma, const float* beta,
                        const int* offv, const int* csrv, const float* dinv,
                        int n, int npg, int zoff) {
    float inv_n = 1.0f / (float)n;
    for (int l = 0; l < 3; ++l) {
      const float* W = Wall + (size_t)l * EMB * EMB;
      const float* gm = (l > 0) ? gamma + (size_t)(l - 1) * EMB : gamma;
      const float* bt = (l > 0) ? beta + (size_t)(l - 1) * EMB : beta;
      gk_prep<<<64, 256, 0, stream>>>(W, stats, gm, bt, inv_n, l > 0 ? 1 : 0,
                                      Wtb, bnscl, bnsh);
      hipMemsetAsync(stats, 0, 256 * 4, stream);
      gk_mm<<<n / 128, 256, 0, stream>>>(Ab, Wtb, bnscl, bnsh, l > 0 ? 1 : 0,
                                         dinv, Gb);
      gk_agg<<<n / 32, 256, 0, stream>>>(Gb, offv, csrv, dinv, Ab, stats);
    }
    gk_pool<<<NGRAPH, 128, 0, stream>>>(Ab, stats, gamma + 2 * EMB, beta + 2 * EMB,
                                        inv_n, z, npg, zoff);
  };

  // ---- ligand path ----
  gk_ligenc<<<NLIG, 128, 0, stream>>>(lig_x, atom_off, atom_emb, Ab);
  run_entity(lig_W, lig_gamma, lig_beta, off_lig, csr_lig, dinv_lig,
             NLIG, NLIG / NGRAPH, 0);

  // ---- receptor path ----
  gk_recw<<<128, 256, 0, stream>>>(rec_w, Wt256);
  gk_recenc<<<NREC / 128, 256, 0, stream>>>(rec_x_float, rec_x_int, rec_emb1,
                                            Wt256, rec_b, Ab);
  run_entity(rec_W, rec_gamma, rec_beta, off_rec, csr_rec, dinv_rec,
             NREC, NREC / NGRAPH, EMB);

  // ---- head ----
  gk_mlp<<<NGRAPH, 128, 0, stream>>>(z, out_w1, out_b1, out_w2, out_b2, out);
}